// Round 6
// baseline (49.224 us; speedup 1.0000x reference)
//
#include <hip/hip_runtime.h>
#include <math.h>

// Problem constants
#define DDIM   1024
#define BATCH  2048
#define MROWS  16384
#define TEMP_INV 10.0f
#define EPSN   1e-8f

// K1: 2048 blocks x 256 threads (4 waves), 8 rows/block
#define NA_BLOCKS 2048
#define NA_THREADS 256
// K2: grid (4,16) = 64 blocks
#define NB_BLOCKS 64
// K3: 1024 blocks x 256 threads, 2 pairs/block, 2 waves/pair
#define NC_BLOCKS 1024
#define NC_THREADS 256

// ws layout: float4 units for big arrays
#define OFF_PART4 0                         // [2048][256] float4 partials (8 MB)
#define OFF_P24   (NA_BLOCKS * 256)         // [16][256] float4 stage-2
#define OFF_S4    (OFF_P24 + 16 * 256)      // [256] float4 final s
// float-unit offsets
#define OFF_LPF   ((OFF_S4 + 256) * 4)      // NC_BLOCKS loss partials
#define OFF_CNT1  (OFF_LPF + NC_BLOCKS)     // ticket for K2 (uint)
#define OFF_CNT2  (OFF_CNT1 + 1)            // ticket for K3 (uint)

__device__ __forceinline__ float wave_sum(float v) {
    v += __shfl_xor(v, 32);
    v += __shfl_xor(v, 16);
    v += __shfl_xor(v, 8);
    v += __shfl_xor(v, 4);
    v += __shfl_xor(v, 2);
    v += __shfl_xor(v, 1);
    return v;
}

__device__ __forceinline__ float softplus_stable(float d) {
    return fmaxf(d, 0.0f) + log1pf(expf(-fabsf(d)));
}

__device__ __forceinline__ void f4acc(float4& a, const float4 v) {
    a.x += v.x; a.y += v.y; a.z += v.z; a.w += v.w;
}

// ---- K1: partial[block][d] = sum over the block's 8 rows of row/||row|| ----
// (round-3 mb_sum, unchanged) + block 0 zeroes the tickets for K2/K3.
__global__ __launch_bounds__(NA_THREADS, 6)
void mb_sum_kernel(const float* __restrict__ mb, float* __restrict__ ws) {
    __shared__ float4 lds4[4][256];
    const int tid  = threadIdx.x;
    const int lane = tid & 63;
    const int wave = tid >> 6;
    const int rbase = blockIdx.x * 8;

    if (blockIdx.x == 0 && tid == 0) {
        ((unsigned int*)ws)[OFF_CNT1] = 0u;
        ((unsigned int*)ws)[OFF_CNT2] = 0u;
    }

    float4 a0 = {0,0,0,0}, a1 = {0,0,0,0}, a2 = {0,0,0,0}, a3 = {0,0,0,0};

    #pragma unroll
    for (int k = 0; k < 2; ++k) {
        const int row = rbase + k * 4 + wave;
        const float4* rp = reinterpret_cast<const float4*>(mb + (size_t)row * DDIM);
        float4 v0 = rp[lane];
        float4 v1 = rp[64 + lane];
        float4 v2 = rp[128 + lane];
        float4 v3 = rp[192 + lane];

        float ssq = v0.x*v0.x + v0.y*v0.y + v0.z*v0.z + v0.w*v0.w
                  + v1.x*v1.x + v1.y*v1.y + v1.z*v1.z + v1.w*v1.w
                  + v2.x*v2.x + v2.y*v2.y + v2.z*v2.z + v2.w*v2.w
                  + v3.x*v3.x + v3.y*v3.y + v3.z*v3.z + v3.w*v3.w;
        ssq = wave_sum(ssq);
        float inv = 1.0f / fmaxf(sqrtf(ssq), EPSN);

        a0.x += v0.x*inv; a0.y += v0.y*inv; a0.z += v0.z*inv; a0.w += v0.w*inv;
        a1.x += v1.x*inv; a1.y += v1.y*inv; a1.z += v1.z*inv; a1.w += v1.w*inv;
        a2.x += v2.x*inv; a2.y += v2.y*inv; a2.z += v2.z*inv; a2.w += v2.w*inv;
        a3.x += v3.x*inv; a3.y += v3.y*inv; a3.z += v3.z*inv; a3.w += v3.w*inv;
    }

    lds4[wave][lane]       = a0;
    lds4[wave][64 + lane]  = a1;
    lds4[wave][128 + lane] = a2;
    lds4[wave][192 + lane] = a3;
    __syncthreads();

    float4 t0 = lds4[0][tid], t1 = lds4[1][tid], t2 = lds4[2][tid], t3 = lds4[3][tid];
    float4 t;
    t.x = t0.x + t1.x + t2.x + t3.x;
    t.y = t0.y + t1.y + t2.y + t3.y;
    t.z = t0.z + t1.z + t2.z + t3.z;
    t.w = t0.w + t1.w + t2.w + t3.w;

    reinterpret_cast<float4*>(ws)[OFF_PART4 + (size_t)blockIdx.x * 256 + tid] = t;
}

// ---- K2: stage-2 partials (round-3 reduce1) + last block folds stage-3 ----
// grid (4,16): bx = 64-float4 col group, by = 128-row chunk.
__global__ __launch_bounds__(256)
void reduce_kernel(float* __restrict__ ws) {
    float4* ws4 = reinterpret_cast<float4*>(ws);
    const int tid = threadIdx.x;
    const int col = tid & 63;
    const int sub = tid >> 6;
    const int c4  = blockIdx.x * 64 + col;
    const int by  = blockIdx.y;

    float4 a = {0,0,0,0};
    #pragma unroll 8
    for (int k = 0; k < 32; ++k) {
        const int r = by * 128 + k * 4 + sub;
        f4acc(a, ws4[OFF_PART4 + (size_t)r * 256 + c4]);
    }

    __shared__ float4 lds[4][64];
    __shared__ int is_last;
    lds[sub][col] = a;
    __syncthreads();
    if (sub == 0) {
        float4 u0 = lds[0][col], u1 = lds[1][col], u2 = lds[2][col], u3 = lds[3][col];
        float4 t;
        t.x = u0.x + u1.x + u2.x + u3.x;
        t.y = u0.y + u1.y + u2.y + u3.y;
        t.z = u0.z + u1.z + u2.z + u3.z;
        t.w = u0.w + u1.w + u2.w + u3.w;
        ws4[OFF_P24 + (size_t)by * 256 + c4] = t;
        __threadfence();            // release this block's stage-2 writes
    }
    __syncthreads();
    if (tid == 0) {
        unsigned int old = atomicAdd(&((unsigned int*)ws)[OFF_CNT1], 1u);
        is_last = (old == NB_BLOCKS - 1);
    }
    __syncthreads();
    if (is_last) {
        __threadfence();            // acquire all blocks' stage-2 writes
        float4 s = {0,0,0,0};
        #pragma unroll
        for (int j = 0; j < 16; ++j)
            f4acc(s, ws4[OFF_P24 + (size_t)j * 256 + tid]);
        ws4[OFF_S4 + tid] = s;
    }
}

// ---- K3: 2 pairs/block, 2 waves/pair; ticket-fused final loss reduce ----
__global__ __launch_bounds__(NC_THREADS, 4)
void img_kernel(const float* __restrict__ img, float* __restrict__ ws,
                float* __restrict__ out) {
    __shared__ float lds5[4][5];
    __shared__ float lds_loss[2];
    __shared__ float lws[4];
    __shared__ int is_last;
    const int tid  = threadIdx.x;
    const int lane = tid & 63;
    const int wave = tid >> 6;
    const int pair = blockIdx.x * 2 + (wave >> 1);   // [0, BATCH)
    const int half = wave & 1;
    const int base = half * 128 + lane;

    const float4* ap = reinterpret_cast<const float4*>(img) + (size_t)pair * 256;
    const float4* bp = reinterpret_cast<const float4*>(img) + (size_t)(pair + BATCH) * 256;
    const float4* sp = reinterpret_cast<const float4*>(ws) + OFF_S4;

    float4 va0 = ap[base], va1 = ap[base + 64];
    float4 vb0 = bp[base], vb1 = bp[base + 64];
    float4 vs0 = sp[base], vs1 = sp[base + 64];

    float ssqa = va0.x*va0.x + va0.y*va0.y + va0.z*va0.z + va0.w*va0.w
               + va1.x*va1.x + va1.y*va1.y + va1.z*va1.z + va1.w*va1.w;
    float ssqb = vb0.x*vb0.x + vb0.y*vb0.y + vb0.z*vb0.z + vb0.w*vb0.w
               + vb1.x*vb1.x + vb1.y*vb1.y + vb1.z*vb1.z + vb1.w*vb1.w;
    float dab  = va0.x*vb0.x + va0.y*vb0.y + va0.z*vb0.z + va0.w*vb0.w
               + va1.x*vb1.x + va1.y*vb1.y + va1.z*vb1.z + va1.w*vb1.w;
    float das  = va0.x*vs0.x + va0.y*vs0.y + va0.z*vs0.z + va0.w*vs0.w
               + va1.x*vs1.x + va1.y*vs1.y + va1.z*vs1.z + va1.w*vs1.w;
    float dbs  = vb0.x*vs0.x + vb0.y*vs0.y + vb0.z*vs0.z + vb0.w*vs0.w
               + vb1.x*vs1.x + vb1.y*vs1.y + vb1.z*vs1.z + vb1.w*vs1.w;

    ssqa = wave_sum(ssqa);
    ssqb = wave_sum(ssqb);
    dab  = wave_sum(dab);
    das  = wave_sum(das);
    dbs  = wave_sum(dbs);

    if (lane == 0) {
        lds5[wave][0] = ssqa; lds5[wave][1] = ssqb; lds5[wave][2] = dab;
        lds5[wave][3] = das;  lds5[wave][4] = dbs;
    }
    __syncthreads();
    if (half == 0 && lane == 0) {
        const int w = wave;
        float sa = lds5[w][0] + lds5[w + 1][0];
        float sb = lds5[w][1] + lds5[w + 1][1];
        float ab = lds5[w][2] + lds5[w + 1][2];
        float as = lds5[w][3] + lds5[w + 1][3];
        float bs = lds5[w][4] + lds5[w + 1][4];
        float ia  = 1.0f / fmaxf(sqrtf(sa), EPSN);
        float ib  = 1.0f / fmaxf(sqrtf(sb), EPSN);
        float pos = ab * ia * ib * TEMP_INV;
        float na  = as * ia * TEMP_INV;
        float nb  = bs * ib * TEMP_INV;
        lds_loss[w >> 1] = softplus_stable(na - pos) + softplus_stable(nb - pos);
    }
    __syncthreads();
    if (tid == 0) {
        ws[OFF_LPF + blockIdx.x] = lds_loss[0] + lds_loss[1];
        __threadfence();            // release this block's loss partial
        unsigned int old = atomicAdd(&((unsigned int*)ws)[OFF_CNT2], 1u);
        is_last = (old == NC_BLOCKS - 1);
    }
    __syncthreads();
    if (is_last) {
        __threadfence();            // acquire all blocks' loss partials
        float v = ws[OFF_LPF + tid]       + ws[OFF_LPF + 256 + tid]
                + ws[OFF_LPF + 512 + tid] + ws[OFF_LPF + 768 + tid];
        v = wave_sum(v);
        if (lane == 0) lws[wave] = v;
        __syncthreads();
        if (tid == 0)
            out[0] = (lws[0] + lws[1] + lws[2] + lws[3]) * (1.0f / (2.0f * BATCH));
    }
}

extern "C" void kernel_launch(void* const* d_in, const int* in_sizes, int n_in,
                              void* d_out, int out_size, void* d_ws, size_t ws_size,
                              hipStream_t stream) {
    const float* img = (const float*)d_in[0];   // [2B, D] fp32
    const float* mb  = (const float*)d_in[1];   // [M, D]  fp32
    float* out = (float*)d_out;
    float* ws  = (float*)d_ws;

    hipLaunchKernelGGL(mb_sum_kernel, dim3(NA_BLOCKS), dim3(NA_THREADS), 0, stream, mb, ws);
    hipLaunchKernelGGL(reduce_kernel, dim3(4, 16),     dim3(256),        0, stream, ws);
    hipLaunchKernelGGL(img_kernel,    dim3(NC_BLOCKS), dim3(NC_THREADS), 0, stream, img, ws, out);
}

// Round 7
// 30.545 us; speedup vs baseline: 1.6115x; 1.6115x over previous
//
#include <hip/hip_runtime.h>
#include <math.h>

// Problem constants
#define DDIM   1024
#define BATCH  2048
#define MROWS  16384
#define TEMP_INV 10.0f
#define EPSN   1e-8f

// K1: 2048 blocks x 256 threads (4 waves), 8 rows/block  (round-3 proven)
#define NA_BLOCKS 2048
#define NA_THREADS 256
// K2: grid (4,8) = 32 blocks, 256-row chunks
#define NCHUNK 8
// K3: 512 blocks x 256 threads, 1 wave/pair (round-3 proven)
#define NC_BLOCKS 512
#define NC_THREADS 256

// ws layout: float4 units for big arrays
#define OFF_PART4 0                         // [2048][256] float4 partials (8 MB)
#define OFF_P24   (NA_BLOCKS * 256)         // [8][256] float4 stage-2
// float-unit offsets
#define OFF_LPF   ((OFF_P24 + NCHUNK * 256) * 4)   // NC_BLOCKS loss partials

__device__ __forceinline__ float wave_sum(float v) {
    v += __shfl_xor(v, 32);
    v += __shfl_xor(v, 16);
    v += __shfl_xor(v, 8);
    v += __shfl_xor(v, 4);
    v += __shfl_xor(v, 2);
    v += __shfl_xor(v, 1);
    return v;
}

__device__ __forceinline__ float softplus_stable(float d) {
    return fmaxf(d, 0.0f) + log1pf(expf(-fabsf(d)));
}

__device__ __forceinline__ void f4acc(float4& a, const float4 v) {
    a.x += v.x; a.y += v.y; a.z += v.z; a.w += v.w;
}

// ---- K1: partial[block][d] = sum over the block's 8 rows of row/||row|| ----
// (round-3 mb_sum, verbatim: full occupancy, no atomics, coalesced write)
__global__ __launch_bounds__(NA_THREADS, 6)
void mb_sum_kernel(const float* __restrict__ mb, float* __restrict__ ws) {
    __shared__ float4 lds4[4][256];
    const int tid  = threadIdx.x;
    const int lane = tid & 63;
    const int wave = tid >> 6;
    const int rbase = blockIdx.x * 8;

    float4 a0 = {0,0,0,0}, a1 = {0,0,0,0}, a2 = {0,0,0,0}, a3 = {0,0,0,0};

    #pragma unroll
    for (int k = 0; k < 2; ++k) {
        const int row = rbase + k * 4 + wave;
        const float4* rp = reinterpret_cast<const float4*>(mb + (size_t)row * DDIM);
        float4 v0 = rp[lane];
        float4 v1 = rp[64 + lane];
        float4 v2 = rp[128 + lane];
        float4 v3 = rp[192 + lane];

        float ssq = v0.x*v0.x + v0.y*v0.y + v0.z*v0.z + v0.w*v0.w
                  + v1.x*v1.x + v1.y*v1.y + v1.z*v1.z + v1.w*v1.w
                  + v2.x*v2.x + v2.y*v2.y + v2.z*v2.z + v2.w*v2.w
                  + v3.x*v3.x + v3.y*v3.y + v3.z*v3.z + v3.w*v3.w;
        ssq = wave_sum(ssq);
        float inv = 1.0f / fmaxf(sqrtf(ssq), EPSN);

        a0.x += v0.x*inv; a0.y += v0.y*inv; a0.z += v0.z*inv; a0.w += v0.w*inv;
        a1.x += v1.x*inv; a1.y += v1.y*inv; a1.z += v1.z*inv; a1.w += v1.w*inv;
        a2.x += v2.x*inv; a2.y += v2.y*inv; a2.z += v2.z*inv; a2.w += v2.w*inv;
        a3.x += v3.x*inv; a3.y += v3.y*inv; a3.z += v3.z*inv; a3.w += v3.w*inv;
    }

    lds4[wave][lane]       = a0;
    lds4[wave][64 + lane]  = a1;
    lds4[wave][128 + lane] = a2;
    lds4[wave][192 + lane] = a3;
    __syncthreads();

    float4 t0 = lds4[0][tid], t1 = lds4[1][tid], t2 = lds4[2][tid], t3 = lds4[3][tid];
    float4 t;
    t.x = t0.x + t1.x + t2.x + t3.x;
    t.y = t0.y + t1.y + t2.y + t3.y;
    t.z = t0.z + t1.z + t2.z + t3.z;
    t.w = t0.w + t1.w + t2.w + t3.w;

    reinterpret_cast<float4*>(ws)[OFF_PART4 + (size_t)blockIdx.x * 256 + tid] = t;
}

// ---- K2: stage-2 partials. grid (4,8): bx = 64-float4 col group, by = 256-row chunk ----
// (round-3 reduce1 pattern: fully coalesced 1 KB/wave reads)
__global__ __launch_bounds__(256)
void reduce1_kernel(float* __restrict__ ws) {
    float4* ws4 = reinterpret_cast<float4*>(ws);
    const int tid = threadIdx.x;
    const int col = tid & 63;
    const int sub = tid >> 6;
    const int c4  = blockIdx.x * 64 + col;
    const int by  = blockIdx.y;

    float4 a = {0,0,0,0};
    #pragma unroll 8
    for (int k = 0; k < 64; ++k) {
        const int r = by * 256 + k * 4 + sub;
        f4acc(a, ws4[OFF_PART4 + (size_t)r * 256 + c4]);
    }

    __shared__ float4 lds[4][64];
    lds[sub][col] = a;
    __syncthreads();
    if (sub == 0) {
        float4 u0 = lds[0][col], u1 = lds[1][col], u2 = lds[2][col], u3 = lds[3][col];
        float4 t;
        t.x = u0.x + u1.x + u2.x + u3.x;
        t.y = u0.y + u1.y + u2.y + u3.y;
        t.z = u0.z + u1.z + u2.z + u3.z;
        t.w = u0.w + u1.w + u2.w + u3.w;
        ws4[OFF_P24 + (size_t)by * 256 + c4] = t;
    }
}

// ---- K3: fold 8 stage-2 rows into LDS s-tile, then 1 wave/pair dots ----
__global__ __launch_bounds__(NC_THREADS)
void img_kernel(const float* __restrict__ img, float* __restrict__ ws) {
    __shared__ float4 s_lds[256];     // the s vector, float4-indexed
    __shared__ float ls[NC_THREADS / 64];
    const int tid  = threadIdx.x;
    const int lane = tid & 63;
    const int wave = tid >> 6;
    const int pair = blockIdx.x * (NC_THREADS / 64) + wave;   // [0, BATCH)

    // cooperative fold of p2[8][256] (4 KB x 8, L2-hot) -> s (4 KB LDS)
    {
        const float4* p2 = reinterpret_cast<const float4*>(ws) + OFF_P24;
        float4 acc = {0,0,0,0};
        #pragma unroll
        for (int j = 0; j < NCHUNK; ++j)
            f4acc(acc, p2[(size_t)j * 256 + tid]);
        s_lds[tid] = acc;
    }
    __syncthreads();

    const float4* ap = reinterpret_cast<const float4*>(img) + (size_t)pair * 256;
    const float4* bp = reinterpret_cast<const float4*>(img) + (size_t)(pair + BATCH) * 256;

    float ssqa = 0.f, ssqb = 0.f, dab = 0.f, das = 0.f, dbs = 0.f;

    #pragma unroll
    for (int c = 0; c < 4; ++c) {
        float4 va = ap[c * 64 + lane];
        float4 vb = bp[c * 64 + lane];
        float4 vs = s_lds[c * 64 + lane];
        ssqa = fmaf(va.x, va.x, ssqa); ssqa = fmaf(va.y, va.y, ssqa);
        ssqa = fmaf(va.z, va.z, ssqa); ssqa = fmaf(va.w, va.w, ssqa);
        ssqb = fmaf(vb.x, vb.x, ssqb); ssqb = fmaf(vb.y, vb.y, ssqb);
        ssqb = fmaf(vb.z, vb.z, ssqb); ssqb = fmaf(vb.w, vb.w, ssqb);
        dab  = fmaf(va.x, vb.x, dab);  dab  = fmaf(va.y, vb.y, dab);
        dab  = fmaf(va.z, vb.z, dab);  dab  = fmaf(va.w, vb.w, dab);
        das  = fmaf(va.x, vs.x, das);  das  = fmaf(va.y, vs.y, das);
        das  = fmaf(va.z, vs.z, das);  das  = fmaf(va.w, vs.w, das);
        dbs  = fmaf(vb.x, vs.x, dbs);  dbs  = fmaf(vb.y, vs.y, dbs);
        dbs  = fmaf(vb.z, vs.z, dbs);  dbs  = fmaf(vb.w, vs.w, dbs);
    }

    ssqa = wave_sum(ssqa);
    ssqb = wave_sum(ssqb);
    dab  = wave_sum(dab);
    das  = wave_sum(das);
    dbs  = wave_sum(dbs);

    if (lane == 0) {
        float ia  = 1.0f / fmaxf(sqrtf(ssqa), EPSN);
        float ib  = 1.0f / fmaxf(sqrtf(ssqb), EPSN);
        float pos = dab * ia * ib * TEMP_INV;
        float na  = das * ia * TEMP_INV;
        float nb  = dbs * ib * TEMP_INV;
        ls[wave] = softplus_stable(na - pos) + softplus_stable(nb - pos);
    }
    __syncthreads();
    if (tid == 0)
        ws[OFF_LPF + blockIdx.x] = ls[0] + ls[1] + ls[2] + ls[3];
}

// ---- K4: final scalar = mean over 2B rows ----
__global__ __launch_bounds__(256)
void final_kernel(const float* __restrict__ ws, float* __restrict__ out) {
    __shared__ float lws[4];
    const int tid  = threadIdx.x;
    const int lane = tid & 63;
    const int wave = tid >> 6;
    float v = ws[OFF_LPF + tid] + ws[OFF_LPF + 256 + tid];
    v = wave_sum(v);
    if (lane == 0) lws[wave] = v;
    __syncthreads();
    if (tid == 0)
        out[0] = (lws[0] + lws[1] + lws[2] + lws[3]) * (1.0f / (2.0f * BATCH));
}

extern "C" void kernel_launch(void* const* d_in, const int* in_sizes, int n_in,
                              void* d_out, int out_size, void* d_ws, size_t ws_size,
                              hipStream_t stream) {
    const float* img = (const float*)d_in[0];   // [2B, D] fp32
    const float* mb  = (const float*)d_in[1];   // [M, D]  fp32
    float* out = (float*)d_out;
    float* ws  = (float*)d_ws;

    hipLaunchKernelGGL(mb_sum_kernel,  dim3(NA_BLOCKS),  dim3(NA_THREADS), 0, stream, mb, ws);
    hipLaunchKernelGGL(reduce1_kernel, dim3(4, NCHUNK),  dim3(256),        0, stream, ws);
    hipLaunchKernelGGL(img_kernel,     dim3(NC_BLOCKS),  dim3(NC_THREADS), 0, stream, img, ws);
    hipLaunchKernelGGL(final_kernel,   dim3(1),          dim3(256),        0, stream, ws, out);
}

// Round 8
// 29.080 us; speedup vs baseline: 1.6927x; 1.0504x over previous
//
#include <hip/hip_runtime.h>
#include <math.h>

// Problem constants
#define DDIM   1024
#define BATCH  2048
#define MROWS  16384
#define TEMP_INV 10.0f
#define EPSN   1e-8f

// K1: 1024 blocks x 256 threads (4 waves), 16 rows/block, 4 rows/wave
#define NA_BLOCKS 1024
#define NA_THREADS 256
// K2: grid (4,8) = 32 blocks, 128-row chunks
#define NCHUNK 8
// K3: 512 blocks x 256 threads, 1 wave/pair (proven)
#define NC_BLOCKS 512
#define NC_THREADS 256

// ws layout: float4 units for big arrays
#define OFF_PART4 0                         // [1024][256] float4 partials (4 MB)
#define OFF_P24   (NA_BLOCKS * 256)         // [8][256] float4 stage-2
// float-unit offsets
#define OFF_LPF   ((OFF_P24 + NCHUNK * 256) * 4)   // NC_BLOCKS loss partials

__device__ __forceinline__ float wave_sum(float v) {
    v += __shfl_xor(v, 32);
    v += __shfl_xor(v, 16);
    v += __shfl_xor(v, 8);
    v += __shfl_xor(v, 4);
    v += __shfl_xor(v, 2);
    v += __shfl_xor(v, 1);
    return v;
}

__device__ __forceinline__ float softplus_stable(float d) {
    return fmaxf(d, 0.0f) + log1pf(expf(-fabsf(d)));
}

__device__ __forceinline__ void f4acc(float4& a, const float4 v) {
    a.x += v.x; a.y += v.y; a.z += v.z; a.w += v.w;
}

__device__ __forceinline__ float dot4(const float4 a, const float4 b) {
    return a.x*b.x + a.y*b.y + a.z*b.z + a.w*b.w;
}

// ---- K1: partial[block][d] = sum over the block's 16 rows of row/||row|| ----
// 4 rows/wave, all 16 loads in flight, interleaved butterfly reduces.
__global__ __launch_bounds__(NA_THREADS, 4)
void mb_sum_kernel(const float* __restrict__ mb, float* __restrict__ ws) {
    __shared__ float4 lds4[4][256];
    const int tid  = threadIdx.x;
    const int lane = tid & 63;
    const int wave = tid >> 6;
    const int rbase = blockIdx.x * 16 + wave * 4;

    const float4* rp0 = reinterpret_cast<const float4*>(mb + (size_t)(rbase + 0) * DDIM);
    const float4* rp1 = reinterpret_cast<const float4*>(mb + (size_t)(rbase + 1) * DDIM);
    const float4* rp2 = reinterpret_cast<const float4*>(mb + (size_t)(rbase + 2) * DDIM);
    const float4* rp3 = reinterpret_cast<const float4*>(mb + (size_t)(rbase + 3) * DDIM);

    // 16 independent float4 loads — all issued before any use
    float4 v00 = rp0[lane], v01 = rp0[64 + lane], v02 = rp0[128 + lane], v03 = rp0[192 + lane];
    float4 v10 = rp1[lane], v11 = rp1[64 + lane], v12 = rp1[128 + lane], v13 = rp1[192 + lane];
    float4 v20 = rp2[lane], v21 = rp2[64 + lane], v22 = rp2[128 + lane], v23 = rp2[192 + lane];
    float4 v30 = rp3[lane], v31 = rp3[64 + lane], v32 = rp3[128 + lane], v33 = rp3[192 + lane];

    float s0 = dot4(v00,v00) + dot4(v01,v01) + dot4(v02,v02) + dot4(v03,v03);
    float s1 = dot4(v10,v10) + dot4(v11,v11) + dot4(v12,v12) + dot4(v13,v13);
    float s2 = dot4(v20,v20) + dot4(v21,v21) + dot4(v22,v22) + dot4(v23,v23);
    float s3 = dot4(v30,v30) + dot4(v31,v31) + dot4(v32,v32) + dot4(v33,v33);

    // 4 interleaved butterfly chains: 4x the reduce throughput, one latency
    #pragma unroll
    for (int sh = 32; sh >= 1; sh >>= 1) {
        s0 += __shfl_xor(s0, sh);
        s1 += __shfl_xor(s1, sh);
        s2 += __shfl_xor(s2, sh);
        s3 += __shfl_xor(s3, sh);
    }
    const float i0 = 1.0f / fmaxf(sqrtf(s0), EPSN);
    const float i1 = 1.0f / fmaxf(sqrtf(s1), EPSN);
    const float i2 = 1.0f / fmaxf(sqrtf(s2), EPSN);
    const float i3 = 1.0f / fmaxf(sqrtf(s3), EPSN);

    float4 a0, a1, a2, a3;
    a0.x = v00.x*i0 + v10.x*i1 + v20.x*i2 + v30.x*i3;
    a0.y = v00.y*i0 + v10.y*i1 + v20.y*i2 + v30.y*i3;
    a0.z = v00.z*i0 + v10.z*i1 + v20.z*i2 + v30.z*i3;
    a0.w = v00.w*i0 + v10.w*i1 + v20.w*i2 + v30.w*i3;
    a1.x = v01.x*i0 + v11.x*i1 + v21.x*i2 + v31.x*i3;
    a1.y = v01.y*i0 + v11.y*i1 + v21.y*i2 + v31.y*i3;
    a1.z = v01.z*i0 + v11.z*i1 + v21.z*i2 + v31.z*i3;
    a1.w = v01.w*i0 + v11.w*i1 + v21.w*i2 + v31.w*i3;
    a2.x = v02.x*i0 + v12.x*i1 + v22.x*i2 + v32.x*i3;
    a2.y = v02.y*i0 + v12.y*i1 + v22.y*i2 + v32.y*i3;
    a2.z = v02.z*i0 + v12.z*i1 + v22.z*i2 + v32.z*i3;
    a2.w = v02.w*i0 + v12.w*i1 + v22.w*i2 + v32.w*i3;
    a3.x = v03.x*i0 + v13.x*i1 + v23.x*i2 + v33.x*i3;
    a3.y = v03.y*i0 + v13.y*i1 + v23.y*i2 + v33.y*i3;
    a3.z = v03.z*i0 + v13.z*i1 + v23.z*i2 + v33.z*i3;
    a3.w = v03.w*i0 + v13.w*i1 + v23.w*i2 + v33.w*i3;

    lds4[wave][lane]       = a0;
    lds4[wave][64 + lane]  = a1;
    lds4[wave][128 + lane] = a2;
    lds4[wave][192 + lane] = a3;
    __syncthreads();

    float4 t0 = lds4[0][tid], t1 = lds4[1][tid], t2 = lds4[2][tid], t3 = lds4[3][tid];
    float4 t;
    t.x = t0.x + t1.x + t2.x + t3.x;
    t.y = t0.y + t1.y + t2.y + t3.y;
    t.z = t0.z + t1.z + t2.z + t3.z;
    t.w = t0.w + t1.w + t2.w + t3.w;

    reinterpret_cast<float4*>(ws)[OFF_PART4 + (size_t)blockIdx.x * 256 + tid] = t;
}

// ---- K2: stage-2 partials. grid (4,8): bx = 64-float4 col group, by = 128-row chunk ----
__global__ __launch_bounds__(256)
void reduce1_kernel(float* __restrict__ ws) {
    float4* ws4 = reinterpret_cast<float4*>(ws);
    const int tid = threadIdx.x;
    const int col = tid & 63;
    const int sub = tid >> 6;
    const int c4  = blockIdx.x * 64 + col;
    const int by  = blockIdx.y;

    float4 a = {0,0,0,0};
    #pragma unroll 8
    for (int k = 0; k < 32; ++k) {
        const int r = by * 128 + k * 4 + sub;
        f4acc(a, ws4[OFF_PART4 + (size_t)r * 256 + c4]);
    }

    __shared__ float4 lds[4][64];
    lds[sub][col] = a;
    __syncthreads();
    if (sub == 0) {
        float4 u0 = lds[0][col], u1 = lds[1][col], u2 = lds[2][col], u3 = lds[3][col];
        float4 t;
        t.x = u0.x + u1.x + u2.x + u3.x;
        t.y = u0.y + u1.y + u2.y + u3.y;
        t.z = u0.z + u1.z + u2.z + u3.z;
        t.w = u0.w + u1.w + u2.w + u3.w;
        ws4[OFF_P24 + (size_t)by * 256 + c4] = t;
    }
}

// ---- K3: fold 8 stage-2 rows into LDS s-tile, then 1 wave/pair dots ----
__global__ __launch_bounds__(NC_THREADS)
void img_kernel(const float* __restrict__ img, float* __restrict__ ws) {
    __shared__ float4 s_lds[256];
    __shared__ float ls[NC_THREADS / 64];
    const int tid  = threadIdx.x;
    const int lane = tid & 63;
    const int wave = tid >> 6;
    const int pair = blockIdx.x * (NC_THREADS / 64) + wave;   // [0, BATCH)

    {
        const float4* p2 = reinterpret_cast<const float4*>(ws) + OFF_P24;
        float4 acc = {0,0,0,0};
        #pragma unroll
        for (int j = 0; j < NCHUNK; ++j)
            f4acc(acc, p2[(size_t)j * 256 + tid]);
        s_lds[tid] = acc;
    }
    __syncthreads();

    const float4* ap = reinterpret_cast<const float4*>(img) + (size_t)pair * 256;
    const float4* bp = reinterpret_cast<const float4*>(img) + (size_t)(pair + BATCH) * 256;

    float ssqa = 0.f, ssqb = 0.f, dab = 0.f, das = 0.f, dbs = 0.f;

    #pragma unroll
    for (int c = 0; c < 4; ++c) {
        float4 va = ap[c * 64 + lane];
        float4 vb = bp[c * 64 + lane];
        float4 vs = s_lds[c * 64 + lane];
        ssqa = fmaf(va.x, va.x, ssqa); ssqa = fmaf(va.y, va.y, ssqa);
        ssqa = fmaf(va.z, va.z, ssqa); ssqa = fmaf(va.w, va.w, ssqa);
        ssqb = fmaf(vb.x, vb.x, ssqb); ssqb = fmaf(vb.y, vb.y, ssqb);
        ssqb = fmaf(vb.z, vb.z, ssqb); ssqb = fmaf(vb.w, vb.w, ssqb);
        dab  = fmaf(va.x, vb.x, dab);  dab  = fmaf(va.y, vb.y, dab);
        dab  = fmaf(va.z, vb.z, dab);  dab  = fmaf(va.w, vb.w, dab);
        das  = fmaf(va.x, vs.x, das);  das  = fmaf(va.y, vs.y, das);
        das  = fmaf(va.z, vs.z, das);  das  = fmaf(va.w, vs.w, das);
        dbs  = fmaf(vb.x, vs.x, dbs);  dbs  = fmaf(vb.y, vs.y, dbs);
        dbs  = fmaf(vb.z, vs.z, dbs);  dbs  = fmaf(vb.w, vs.w, dbs);
    }

    ssqa = wave_sum(ssqa);
    ssqb = wave_sum(ssqb);
    dab  = wave_sum(dab);
    das  = wave_sum(das);
    dbs  = wave_sum(dbs);

    if (lane == 0) {
        float ia  = 1.0f / fmaxf(sqrtf(ssqa), EPSN);
        float ib  = 1.0f / fmaxf(sqrtf(ssqb), EPSN);
        float pos = dab * ia * ib * TEMP_INV;
        float na  = das * ia * TEMP_INV;
        float nb  = dbs * ib * TEMP_INV;
        ls[wave] = softplus_stable(na - pos) + softplus_stable(nb - pos);
    }
    __syncthreads();
    if (tid == 0)
        ws[OFF_LPF + blockIdx.x] = ls[0] + ls[1] + ls[2] + ls[3];
}

// ---- K4: final scalar = mean over 2B rows ----
__global__ __launch_bounds__(256)
void final_kernel(const float* __restrict__ ws, float* __restrict__ out) {
    __shared__ float lws[4];
    const int tid  = threadIdx.x;
    const int lane = tid & 63;
    const int wave = tid >> 6;
    float v = ws[OFF_LPF + tid] + ws[OFF_LPF + 256 + tid];
    v = wave_sum(v);
    if (lane == 0) lws[wave] = v;
    __syncthreads();
    if (tid == 0)
        out[0] = (lws[0] + lws[1] + lws[2] + lws[3]) * (1.0f / (2.0f * BATCH));
}

extern "C" void kernel_launch(void* const* d_in, const int* in_sizes, int n_in,
                              void* d_out, int out_size, void* d_ws, size_t ws_size,
                              hipStream_t stream) {
    const float* img = (const float*)d_in[0];   // [2B, D] fp32
    const float* mb  = (const float*)d_in[1];   // [M, D]  fp32
    float* out = (float*)d_out;
    float* ws  = (float*)d_ws;

    hipLaunchKernelGGL(mb_sum_kernel,  dim3(NA_BLOCKS), dim3(NA_THREADS), 0, stream, mb, ws);
    hipLaunchKernelGGL(reduce1_kernel, dim3(4, NCHUNK), dim3(256),        0, stream, ws);
    hipLaunchKernelGGL(img_kernel,     dim3(NC_BLOCKS), dim3(NC_THREADS), 0, stream, img, ws);
    hipLaunchKernelGGL(final_kernel,   dim3(1),         dim3(256),        0, stream, ws, out);
}

// Round 9
// 28.683 us; speedup vs baseline: 1.7161x; 1.0138x over previous
//
#include <hip/hip_runtime.h>
#include <math.h>

// Problem constants
#define DDIM   1024
#define BATCH  2048
#define MROWS  16384
#define TEMP_INV 10.0f
#define EPSN   1e-8f

// K1: 1024 blocks x 256 threads (4 waves), 16 rows/block, 4 rows/wave
#define NA_BLOCKS 1024
#define NA_THREADS 256
// K2: grid (4,8) = 32 blocks, 128-row chunks
#define NCHUNK 8
// K3: 512 blocks x 256 threads, 1 wave/pair (proven)
#define NC_BLOCKS 512
#define NC_THREADS 256

// ws layout: float4 units for big arrays
#define OFF_PART4 0                         // [1024][256] float4 partials (4 MB)
#define OFF_P24   (NA_BLOCKS * 256)         // [8][256] float4 stage-2
// float-unit offsets
#define OFF_LPF   ((OFF_P24 + NCHUNK * 256) * 4)   // NC_BLOCKS loss partials

typedef float f32x4 __attribute__((ext_vector_type(4)));

__device__ __forceinline__ float4 ldnt4(const float4* p) {
    f32x4 v = __builtin_nontemporal_load(reinterpret_cast<const f32x4*>(p));
    float4 r; r.x = v.x; r.y = v.y; r.z = v.z; r.w = v.w;
    return r;
}

__device__ __forceinline__ float wave_sum(float v) {
    v += __shfl_xor(v, 32);
    v += __shfl_xor(v, 16);
    v += __shfl_xor(v, 8);
    v += __shfl_xor(v, 4);
    v += __shfl_xor(v, 2);
    v += __shfl_xor(v, 1);
    return v;
}

__device__ __forceinline__ float softplus_stable(float d) {
    return fmaxf(d, 0.0f) + log1pf(expf(-fabsf(d)));
}

__device__ __forceinline__ void f4acc(float4& a, const float4 v) {
    a.x += v.x; a.y += v.y; a.z += v.z; a.w += v.w;
}

__device__ __forceinline__ float dot4(const float4 a, const float4 b) {
    return a.x*b.x + a.y*b.y + a.z*b.z + a.w*b.w;
}

// ---- K1: partial[block][d] = sum over the block's 16 rows of row/||row|| ----
// R8 structure, loads switched to NON-TEMPORAL (single-variable A/B vs R8).
__global__ __launch_bounds__(NA_THREADS, 4)
void mb_sum_kernel(const float* __restrict__ mb, float* __restrict__ ws) {
    __shared__ float4 lds4[4][256];
    const int tid  = threadIdx.x;
    const int lane = tid & 63;
    const int wave = tid >> 6;
    const int rbase = blockIdx.x * 16 + wave * 4;

    const float4* rp0 = reinterpret_cast<const float4*>(mb + (size_t)(rbase + 0) * DDIM);
    const float4* rp1 = reinterpret_cast<const float4*>(mb + (size_t)(rbase + 1) * DDIM);
    const float4* rp2 = reinterpret_cast<const float4*>(mb + (size_t)(rbase + 2) * DDIM);
    const float4* rp3 = reinterpret_cast<const float4*>(mb + (size_t)(rbase + 3) * DDIM);

    // 16 independent nt float4 loads — all issued before any use
    float4 v00 = ldnt4(rp0 + lane), v01 = ldnt4(rp0 + 64 + lane),
           v02 = ldnt4(rp0 + 128 + lane), v03 = ldnt4(rp0 + 192 + lane);
    float4 v10 = ldnt4(rp1 + lane), v11 = ldnt4(rp1 + 64 + lane),
           v12 = ldnt4(rp1 + 128 + lane), v13 = ldnt4(rp1 + 192 + lane);
    float4 v20 = ldnt4(rp2 + lane), v21 = ldnt4(rp2 + 64 + lane),
           v22 = ldnt4(rp2 + 128 + lane), v23 = ldnt4(rp2 + 192 + lane);
    float4 v30 = ldnt4(rp3 + lane), v31 = ldnt4(rp3 + 64 + lane),
           v32 = ldnt4(rp3 + 128 + lane), v33 = ldnt4(rp3 + 192 + lane);

    float s0 = dot4(v00,v00) + dot4(v01,v01) + dot4(v02,v02) + dot4(v03,v03);
    float s1 = dot4(v10,v10) + dot4(v11,v11) + dot4(v12,v12) + dot4(v13,v13);
    float s2 = dot4(v20,v20) + dot4(v21,v21) + dot4(v22,v22) + dot4(v23,v23);
    float s3 = dot4(v30,v30) + dot4(v31,v31) + dot4(v32,v32) + dot4(v33,v33);

    #pragma unroll
    for (int sh = 32; sh >= 1; sh >>= 1) {
        s0 += __shfl_xor(s0, sh);
        s1 += __shfl_xor(s1, sh);
        s2 += __shfl_xor(s2, sh);
        s3 += __shfl_xor(s3, sh);
    }
    const float i0 = 1.0f / fmaxf(sqrtf(s0), EPSN);
    const float i1 = 1.0f / fmaxf(sqrtf(s1), EPSN);
    const float i2 = 1.0f / fmaxf(sqrtf(s2), EPSN);
    const float i3 = 1.0f / fmaxf(sqrtf(s3), EPSN);

    float4 a0, a1, a2, a3;
    a0.x = v00.x*i0 + v10.x*i1 + v20.x*i2 + v30.x*i3;
    a0.y = v00.y*i0 + v10.y*i1 + v20.y*i2 + v30.y*i3;
    a0.z = v00.z*i0 + v10.z*i1 + v20.z*i2 + v30.z*i3;
    a0.w = v00.w*i0 + v10.w*i1 + v20.w*i2 + v30.w*i3;
    a1.x = v01.x*i0 + v11.x*i1 + v21.x*i2 + v31.x*i3;
    a1.y = v01.y*i0 + v11.y*i1 + v21.y*i2 + v31.y*i3;
    a1.z = v01.z*i0 + v11.z*i1 + v21.z*i2 + v31.z*i3;
    a1.w = v01.w*i0 + v11.w*i1 + v21.w*i2 + v31.w*i3;
    a2.x = v02.x*i0 + v12.x*i1 + v22.x*i2 + v32.x*i3;
    a2.y = v02.y*i0 + v12.y*i1 + v22.y*i2 + v32.y*i3;
    a2.z = v02.z*i0 + v12.z*i1 + v22.z*i2 + v32.z*i3;
    a2.w = v02.w*i0 + v12.w*i1 + v22.w*i2 + v32.w*i3;
    a3.x = v03.x*i0 + v13.x*i1 + v23.x*i2 + v33.x*i3;
    a3.y = v03.y*i0 + v13.y*i1 + v23.y*i2 + v33.y*i3;
    a3.z = v03.z*i0 + v13.z*i1 + v23.z*i2 + v33.z*i3;
    a3.w = v03.w*i0 + v13.w*i1 + v23.w*i2 + v33.w*i3;

    lds4[wave][lane]       = a0;
    lds4[wave][64 + lane]  = a1;
    lds4[wave][128 + lane] = a2;
    lds4[wave][192 + lane] = a3;
    __syncthreads();

    float4 t0 = lds4[0][tid], t1 = lds4[1][tid], t2 = lds4[2][tid], t3 = lds4[3][tid];
    float4 t;
    t.x = t0.x + t1.x + t2.x + t3.x;
    t.y = t0.y + t1.y + t2.y + t3.y;
    t.z = t0.z + t1.z + t2.z + t3.z;
    t.w = t0.w + t1.w + t2.w + t3.w;

    reinterpret_cast<float4*>(ws)[OFF_PART4 + (size_t)blockIdx.x * 256 + tid] = t;
}

// ---- K2: stage-2 partials. grid (4,8): bx = 64-float4 col group, by = 128-row chunk ----
__global__ __launch_bounds__(256)
void reduce1_kernel(float* __restrict__ ws) {
    float4* ws4 = reinterpret_cast<float4*>(ws);
    const int tid = threadIdx.x;
    const int col = tid & 63;
    const int sub = tid >> 6;
    const int c4  = blockIdx.x * 64 + col;
    const int by  = blockIdx.y;

    float4 a = {0,0,0,0};
    #pragma unroll 8
    for (int k = 0; k < 32; ++k) {
        const int r = by * 128 + k * 4 + sub;
        f4acc(a, ws4[OFF_PART4 + (size_t)r * 256 + c4]);
    }

    __shared__ float4 lds[4][64];
    lds[sub][col] = a;
    __syncthreads();
    if (sub == 0) {
        float4 u0 = lds[0][col], u1 = lds[1][col], u2 = lds[2][col], u3 = lds[3][col];
        float4 t;
        t.x = u0.x + u1.x + u2.x + u3.x;
        t.y = u0.y + u1.y + u2.y + u3.y;
        t.z = u0.z + u1.z + u2.z + u3.z;
        t.w = u0.w + u1.w + u2.w + u3.w;
        ws4[OFF_P24 + (size_t)by * 256 + c4] = t;
    }
}

// ---- K3: fold 8 stage-2 rows into LDS s-tile, then 1 wave/pair dots ----
__global__ __launch_bounds__(NC_THREADS)
void img_kernel(const float* __restrict__ img, float* __restrict__ ws) {
    __shared__ float4 s_lds[256];
    __shared__ float ls[NC_THREADS / 64];
    const int tid  = threadIdx.x;
    const int lane = tid & 63;
    const int wave = tid >> 6;
    const int pair = blockIdx.x * (NC_THREADS / 64) + wave;   // [0, BATCH)

    {
        const float4* p2 = reinterpret_cast<const float4*>(ws) + OFF_P24;
        float4 acc = {0,0,0,0};
        #pragma unroll
        for (int j = 0; j < NCHUNK; ++j)
            f4acc(acc, p2[(size_t)j * 256 + tid]);
        s_lds[tid] = acc;
    }
    __syncthreads();

    const float4* ap = reinterpret_cast<const float4*>(img) + (size_t)pair * 256;
    const float4* bp = reinterpret_cast<const float4*>(img) + (size_t)(pair + BATCH) * 256;

    float ssqa = 0.f, ssqb = 0.f, dab = 0.f, das = 0.f, dbs = 0.f;

    #pragma unroll
    for (int c = 0; c < 4; ++c) {
        float4 va = ap[c * 64 + lane];
        float4 vb = bp[c * 64 + lane];
        float4 vs = s_lds[c * 64 + lane];
        ssqa = fmaf(va.x, va.x, ssqa); ssqa = fmaf(va.y, va.y, ssqa);
        ssqa = fmaf(va.z, va.z, ssqa); ssqa = fmaf(va.w, va.w, ssqa);
        ssqb = fmaf(vb.x, vb.x, ssqb); ssqb = fmaf(vb.y, vb.y, ssqb);
        ssqb = fmaf(vb.z, vb.z, ssqb); ssqb = fmaf(vb.w, vb.w, ssqb);
        dab  = fmaf(va.x, vb.x, dab);  dab  = fmaf(va.y, vb.y, dab);
        dab  = fmaf(va.z, vb.z, dab);  dab  = fmaf(va.w, vb.w, dab);
        das  = fmaf(va.x, vs.x, das);  das  = fmaf(va.y, vs.y, das);
        das  = fmaf(va.z, vs.z, das);  das  = fmaf(va.w, vs.w, das);
        dbs  = fmaf(vb.x, vs.x, dbs);  dbs  = fmaf(vb.y, vs.y, dbs);
        dbs  = fmaf(vb.z, vs.z, dbs);  dbs  = fmaf(vb.w, vs.w, dbs);
    }

    ssqa = wave_sum(ssqa);
    ssqb = wave_sum(ssqb);
    dab  = wave_sum(dab);
    das  = wave_sum(das);
    dbs  = wave_sum(dbs);

    if (lane == 0) {
        float ia  = 1.0f / fmaxf(sqrtf(ssqa), EPSN);
        float ib  = 1.0f / fmaxf(sqrtf(ssqb), EPSN);
        float pos = dab * ia * ib * TEMP_INV;
        float na  = das * ia * TEMP_INV;
        float nb  = dbs * ib * TEMP_INV;
        ls[wave] = softplus_stable(na - pos) + softplus_stable(nb - pos);
    }
    __syncthreads();
    if (tid == 0)
        ws[OFF_LPF + blockIdx.x] = ls[0] + ls[1] + ls[2] + ls[3];
}

// ---- K4: final scalar = mean over 2B rows ----
__global__ __launch_bounds__(256)
void final_kernel(const float* __restrict__ ws, float* __restrict__ out) {
    __shared__ float lws[4];
    const int tid  = threadIdx.x;
    const int lane = tid & 63;
    const int wave = tid >> 6;
    float v = ws[OFF_LPF + tid] + ws[OFF_LPF + 256 + tid];
    v = wave_sum(v);
    if (lane == 0) lws[wave] = v;
    __syncthreads();
    if (tid == 0)
        out[0] = (lws[0] + lws[1] + lws[2] + lws[3]) * (1.0f / (2.0f * BATCH));
}

extern "C" void kernel_launch(void* const* d_in, const int* in_sizes, int n_in,
                              void* d_out, int out_size, void* d_ws, size_t ws_size,
                              hipStream_t stream) {
    const float* img = (const float*)d_in[0];   // [2B, D] fp32
    const float* mb  = (const float*)d_in[1];   // [M, D]  fp32
    float* out = (float*)d_out;
    float* ws  = (float*)d_ws;

    hipLaunchKernelGGL(mb_sum_kernel,  dim3(NA_BLOCKS), dim3(NA_THREADS), 0, stream, mb, ws);
    hipLaunchKernelGGL(reduce1_kernel, dim3(4, NCHUNK), dim3(256),        0, stream, ws);
    hipLaunchKernelGGL(img_kernel,     dim3(NC_BLOCKS), dim3(NC_THREADS), 0, stream, img, ws);
    hipLaunchKernelGGL(final_kernel,   dim3(1),         dim3(256),        0, stream, ws, out);
}